// Round 3
// baseline (353.620 us; speedup 1.0000x reference)
//
#include <hip/hip_runtime.h>

// LoRA forward: out = x @ (A @ B * scale)  ==  ((x @ A) * scale) @ B
// x: [8192, 4096] fp32, A: [4096, 8] -> At[8][4096] in ws, B: [8, 4096].
//
// R2 post-mortem: VGPR=104 capped residency (occupancy 18%), latency-bound
// at 2.4 TB/s. R3: register diet — loop-reorder phase 1, tv coefficients in
// SGPRs (readfirstlane), __launch_bounds__(256,6), nontemporal out stores.

#define DIM    4096
#define DIM4   (DIM / 4)
#define RANK   8
#define LORA_SCALE 2.0f
#define BLOCK  256
#define CHUNK  4      // DIM4 / BLOCK
#define RPB    4      // rows of x per block

typedef float f32x4 __attribute__((ext_vector_type(4)));

// ---- Kernel 1: At[r][i] = A[i][r] (tiny) ----
__global__ __launch_bounds__(BLOCK) void transpose_A_kernel(
    const float* __restrict__ A, float* __restrict__ At)
{
    const int o = blockIdx.x * BLOCK + threadIdx.x;   // 0 .. 8*4096-1
    const int r = o >> 12;
    const int i = o & (DIM - 1);
    At[o] = A[(size_t)i * RANK + r];
}

__device__ __forceinline__ float bcast0(float v) {
    return __int_as_float(__builtin_amdgcn_readfirstlane(__float_as_int(v)));
}

// ---- Kernel 2: fused ((x@A)*s)@B, 4 rows per block ----
__global__ __launch_bounds__(BLOCK, 6) void lora_fused_kernel(
    const float* __restrict__ x,
    const float* __restrict__ At,
    const float* __restrict__ B,
    float* __restrict__ out)
{
    const int tid  = threadIdx.x;
    const int row0 = blockIdx.x * RPB;
    const float4* x4  = (const float4*)x;
    const float4* At4 = (const float4*)At;
    const float4* B4  = (const float4*)B;

    // ---- Phase 1: acc[m][r] = sum_i x[row0+m][i] * At[r][i] ----
    float acc[RPB][RANK];
#pragma unroll
    for (int m = 0; m < RPB; ++m)
#pragma unroll
        for (int r = 0; r < RANK; ++r) acc[m][r] = 0.0f;

#pragma unroll
    for (int k = 0; k < CHUNK; ++k) {
        const int i4 = tid + BLOCK * k;
        float4 xv[RPB];
#pragma unroll
        for (int m = 0; m < RPB; ++m)
            xv[m] = x4[(size_t)(row0 + m) * DIM4 + i4];
#pragma unroll
        for (int r = 0; r < RANK; ++r) {
            const float4 a = At4[r * DIM4 + i4];
#pragma unroll
            for (int m = 0; m < RPB; ++m) {
                acc[m][r] += xv[m].x * a.x + xv[m].y * a.y
                           + xv[m].z * a.z + xv[m].w * a.w;
            }
        }
    }

    // ---- Phase 2: block reduction ----
#pragma unroll
    for (int m = 0; m < RPB; ++m)
#pragma unroll
        for (int r = 0; r < RANK; ++r)
#pragma unroll
            for (int off = 32; off > 0; off >>= 1)
                acc[m][r] += __shfl_down(acc[m][r], off, 64);

    __shared__ float red[BLOCK / 64][RPB][RANK];
    __shared__ float tf[RPB * RANK];
    const int wave = tid >> 6;
    const int lane = tid & 63;
    if (lane == 0) {
#pragma unroll
        for (int m = 0; m < RPB; ++m)
#pragma unroll
            for (int r = 0; r < RANK; ++r) red[wave][m][r] = acc[m][r];
    }
    __syncthreads();
    if (tid < RPB * RANK) {
        const int m = tid >> 3;
        const int r = tid & 7;
        tf[tid] = (red[0][m][r] + red[1][m][r] + red[2][m][r] + red[3][m][r])
                  * LORA_SCALE;
    }
    __syncthreads();

    // Wave-uniform coefficients -> SGPRs (frees 32 VGPRs in phase 3).
    float tv[RPB][RANK];
#pragma unroll
    for (int m = 0; m < RPB; ++m)
#pragma unroll
        for (int r = 0; r < RANK; ++r)
            tv[m][r] = bcast0(tf[m * RANK + r]);

    // ---- Phase 3: out[row0+m][i] = sum_r tv[m][r] * B[r][i] ----
#pragma unroll
    for (int k = 0; k < CHUNK; ++k) {
        const int i4 = tid + BLOCK * k;
        float4 o[RPB];
#pragma unroll
        for (int m = 0; m < RPB; ++m) o[m] = make_float4(0.f, 0.f, 0.f, 0.f);
#pragma unroll
        for (int r = 0; r < RANK; ++r) {
            const float4 b = B4[r * DIM4 + i4];
#pragma unroll
            for (int m = 0; m < RPB; ++m) {
                o[m].x += tv[m][r] * b.x;
                o[m].y += tv[m][r] * b.y;
                o[m].z += tv[m][r] * b.z;
                o[m].w += tv[m][r] * b.w;
            }
        }
#pragma unroll
        for (int m = 0; m < RPB; ++m) {
            f32x4 v = { o[m].x, o[m].y, o[m].z, o[m].w };
            f32x4* dst = (f32x4*)out + (size_t)(row0 + m) * DIM4 + i4;
            __builtin_nontemporal_store(v, dst);
        }
    }
}

extern "C" void kernel_launch(void* const* d_in, const int* in_sizes, int n_in,
                              void* d_out, int out_size, void* d_ws, size_t ws_size,
                              hipStream_t stream) {
    const float* x = (const float*)d_in[0];
    const float* A = (const float*)d_in[1];
    const float* B = (const float*)d_in[2];
    float* out = (float*)d_out;
    float* At  = (float*)d_ws;                // 8*4096 floats = 128 KiB

    const int rows = in_sizes[0] / DIM;       // 8192

    transpose_A_kernel<<<(RANK * DIM) / BLOCK, BLOCK, 0, stream>>>(A, At);
    lora_fused_kernel<<<rows / RPB, BLOCK, 0, stream>>>(x, At, B, out);
}